// Round 1
// baseline (1167.076 us; speedup 1.0000x reference)
//
#include <hip/hip_runtime.h>
#include <hip/hip_cooperative_groups.h>
#include <cstdint>
#include <cstddef>

namespace cg = cooperative_groups;

// Problem constants (fixed by reference).
#define BATCH 16
#define SEQ   4096
#define NS    512
#define TLAG  128            // truncation: ||A^128|| ~ 1e-5 -> error ~1e-4 << bf16 noise
#define PADR  128            // zero left-pad rows in padded x buffer
#define PS    (SEQ + PADR)   // 4224 padded rows per batch
#define CTILE 128            // conv time-tile rows per block
#define XROWS (CTILE + TLAG - 1)   // 255 staged rows
#define XSTR  72             // LDS row stride in u16 (144 B = 9*16B)

typedef unsigned short u16;
typedef unsigned int   u32;
typedef short bf16x8 __attribute__((ext_vector_type(8)));   // 8 bf16 = 4 VGPRs
typedef float f32x4  __attribute__((ext_vector_type(4)));   // MFMA accumulator

__device__ __forceinline__ u16 f2bf(float f) {
    u32 u = __builtin_bit_cast(u32, f);
    return (u16)((u + 0x7FFFu + ((u >> 16) & 1u)) >> 16);   // RNE
}
__device__ __forceinline__ float bf2f(u16 h) {
    return __builtin_bit_cast(float, (u32)h << 16);
}

// ---------------------------------------------------------------------------
// gemm_tile64: one 64(M)x64(N) output tile, K = 512, bf16 in / fp32 acc /
// bf16 out. apM already offset to this tile's first row. bT is B^T
// ([N_total][512]); n0 selects the 64-col slice. Optional row-major out
// (oRM, already row-offset) and transposed out (oT with absolute row rowT).
// block = 256 (4 waves x 16 rows). Layouts verified in round 1.
// ---------------------------------------------------------------------------
__device__ __forceinline__ void gemm_tile64(const u16* __restrict__ apM, int lda,
                                            const u16* __restrict__ bT, int ldbt, int n0,
                                            u16* __restrict__ oRM, int ldo,
                                            u16* __restrict__ oT, int ldoT, int rowT)
{
    const int tid = threadIdx.x;
    const int w = tid >> 6, l = tid & 63;
    const int lr = l & 15, q8 = (l >> 4) * 8;

    const u16* ap  = apM + (size_t)(w * 16 + lr) * lda + q8;
    const u16* bp0 = bT  + (size_t)(n0 + lr) * ldbt + q8;

    f32x4 acc[4];
    const f32x4 zero = {0.f, 0.f, 0.f, 0.f};
    #pragma unroll
    for (int nt = 0; nt < 4; ++nt) acc[nt] = zero;

    #pragma unroll 4
    for (int ks = 0; ks < 16; ++ks) {
        const bf16x8 a = *(const bf16x8*)(ap + ks * 32);
        #pragma unroll
        for (int nt = 0; nt < 4; ++nt) {
            const bf16x8 bfr = *(const bf16x8*)(bp0 + (size_t)nt * 16 * ldbt + ks * 32);
            acc[nt] = __builtin_amdgcn_mfma_f32_16x16x32_bf16(a, bfr, acc[nt], 0, 0, 0);
        }
    }

    const int rr = (l >> 4) * 4;    // C/D: row = (lane>>4)*4 + reg, col = lane&15
    #pragma unroll
    for (int nt = 0; nt < 4; ++nt) {
        const int col = n0 + nt * 16 + lr;
        if (oRM) {
            #pragma unroll
            for (int r = 0; r < 4; ++r)
                oRM[(size_t)(w * 16 + rr + r) * ldo + col] = f2bf(acc[nt][r]);
        }
        if (oT) {
            ushort4 pk;
            pk.x = f2bf(acc[nt][0]); pk.y = f2bf(acc[nt][1]);
            pk.z = f2bf(acc[nt][2]); pk.w = f2bf(acc[nt][3]);
            *(ushort4*)(oT + (size_t)col * ldoT + rowT + w * 16 + rr) = pk;
        }
    }
}

// ---------------------------------------------------------------------------
// chain_kernel: ONE cooperative launch for the entire setup chain.
//   phase 0 : input conversion (x->xbf padded, A->Ap0/ApT0, B->BT, C->W_0)
//   phase 1..7 : W-chain doubling levels (expansion + squaring fused)
//   phase 8 : Gtmp[m] = W_m @ B
//   phase 9 : repack Gtmp -> Gsw (B-fragment order), fold D into lag 0
// 512 blocks x 256 threads = 2 blocks/CU co-resident; grid.sync() between
// phases replaces 9 dependent stream launches. __threadfence() (agent scope)
// before each sync handles cross-XCD L2 visibility.
// ---------------------------------------------------------------------------
__global__ __launch_bounds__(256, 1) void chain_kernel(const float* __restrict__ x,
                                                       const float* __restrict__ A,
                                                       const float* __restrict__ B,
                                                       const float* __restrict__ C,
                                                       const float* __restrict__ D,
                                                       u16* __restrict__ xbf,
                                                       u16* __restrict__ Ap0,
                                                       u16* __restrict__ Ap1,
                                                       u16* __restrict__ ApT0,
                                                       u16* __restrict__ ApT1,
                                                       u16* __restrict__ BT,
                                                       u16* __restrict__ Wall,
                                                       u16* __restrict__ Gtmp,
                                                       u16* __restrict__ Gsw)
{
    cg::grid_group grid = cg::this_grid();
    const int tid = threadIdx.x;

    // ---- phase 0: prep (grid-stride over the old 5504 virtual blocks) ----
    for (int vb = blockIdx.x; vb < 5504; vb += 512) {
        if (vb < 4224) {
            const int id = vb * 256 + tid;               // 16*4224*16 = 1,081,344
            const int b   = id / (PS * 16);
            const int rem = id - b * (PS * 16);
            const int p   = rem >> 4;
            const int g   = id & 15;
            ushort4 o;
            if (p < PADR) {
                o.x = 0; o.y = 0; o.z = 0; o.w = 0;
            } else {
                const float4 v = *(const float4*)(x + ((size_t)b * SEQ + (p - PADR)) * 64 + g * 4);
                o.x = f2bf(v.x); o.y = f2bf(v.y); o.z = f2bf(v.z); o.w = f2bf(v.w);
            }
            *(ushort4*)(xbf + ((size_t)b * PS + p) * 64 + g * 4) = o;
        } else {
            const int id = (vb - 4224) * 256 + tid;      // 327,680 total
            if (id < 262144) {                           // A: 512x512
                const int r = id >> 9, c = id & 511;
                const u16 v = f2bf(A[id]);
                Ap0[id] = v;
                ApT0[(size_t)c * 512 + r] = v;
                (void)r;
            } else if (id < 262144 + 32768) {            // B: 512x64 -> B^T
                const int i = id - 262144;
                const int k = i >> 6, c = i & 63;
                BT[(size_t)c * 512 + k] = f2bf(B[i]);
            } else if (id < 262144 + 65536) {            // C: 64x512 -> W_0
                const int i = id - 262144 - 32768;
                Wall[i] = f2bf(C[i]);
            }
        }
    }
    __threadfence();
    grid.sync();

    // ---- phases 1..7: W-chain doubling levels ----
    u16* ApCur  = Ap0;  u16* ApTCur  = ApT0;
    u16* ApNext = Ap1;  u16* ApTNext = ApT1;
    int h = 1;
    while (h < TLAG) {
        const int nexp  = (h < TLAG - h) ? h : (TLAG - h);
        const int do_sq = (2 * h < TLAG) ? 1 : 0;
        const int ntiles = 8 * (nexp + (do_sq ? 8 : 0));
        for (int t = blockIdx.x; t < ntiles; t += 512) {
            const int n0 = (t & 7) * 64;
            const int by = t >> 3;
            if (by < nexp) {
                gemm_tile64(Wall + (size_t)by * 64 * NS, NS, ApTCur, NS, n0,
                            Wall + (size_t)(h + by) * 64 * NS, NS, nullptr, 0, 0);
            } else {
                const int j = by - nexp;
                gemm_tile64(ApCur + (size_t)j * 64 * NS, NS, ApTCur, NS, n0,
                            ApNext + (size_t)j * 64 * NS, NS, ApTNext, NS, j * 64);
            }
        }
        if (do_sq) {
            u16* tmp;
            tmp = ApCur;  ApCur  = ApNext;  ApNext  = tmp;
            tmp = ApTCur; ApTCur = ApTNext; ApTNext = tmp;
        }
        h += nexp;
        __threadfence();
        grid.sync();
    }

    // ---- phase 8: Gtmp[m*64+o][i] = (W_m @ B)[o][i] ----
    for (int t = blockIdx.x; t < TLAG; t += 512) {
        gemm_tile64(Wall + (size_t)t * 64 * NS, NS, BT, NS, 0,
                    Gtmp + (size_t)t * 64 * 64, 64, nullptr, 0, 0);
    }
    __threadfence();
    grid.sync();

    // ---- phase 9: repack Gtmp -> Gsw in exact B-fragment order ----
    {
        const int id = blockIdx.x * 256 + tid;           // need 65,536 ids
        if (id < 65536) {
            const int l  = id & 63;
            const int fi = id >> 6;
            const int m  = fi >> 3;
            const int ks = (fi >> 2) & 1;
            const int nt = fi & 3;
            const int o  = nt * 16 + (l & 15);
            const int q8 = (l >> 4) * 8;

            u16 v[8];
            #pragma unroll
            for (int j = 0; j < 8; ++j) {
                const int i = ks * 32 + q8 + j;
                u16 g = Gtmp[(size_t)(m * 64 + o) * 64 + i];
                if (m == 0) g = f2bf(bf2f(g) + D[o * 64 + i]);
                v[j] = g;
            }
            ushort4* dst = (ushort4*)(Gsw + (size_t)id * 8);
            ushort4 p0; p0.x = v[0]; p0.y = v[1]; p0.z = v[2]; p0.w = v[3];
            ushort4 p1; p1.x = v[4]; p1.y = v[5]; p1.z = v[6]; p1.w = v[7];
            dst[0] = p0; dst[1] = p1;
        }
    }
}

// ---------------------------------------------------------------------------
// conv_kernel: y[b, t0+tau, o] = sum_{m<128} sum_i G_m[o][i] x[t0+tau-m][i]
// UNCHANGED from previous round (78.5 us, MfmaUtil 37%) to isolate the
// setup-chain experiment.
// ---------------------------------------------------------------------------
__global__ __launch_bounds__(256, 2) void conv_kernel(const u16* __restrict__ xbf,
                                                      const u16* __restrict__ gsw,
                                                      float* __restrict__ y)
{
    __shared__ u16 Xs[XROWS * XSTR];   // 36,720 B -> >=2 blocks/CU

    const int tid = threadIdx.x;
    const int b  = blockIdx.y;
    const int t0 = blockIdx.x * CTILE;

    // Stage padded rows [t0+1 .. t0+255] (= times t0-127 .. t0+127) into LDS.
    {
        const int g = tid & 7;
        int r = tid >> 3;
        const u16* src = xbf + ((size_t)b * PS + t0 + 1) * 64 + g * 8;
        #pragma unroll
        for (int it = 0; it < 8; ++it, r += 32) {
            if (r < XROWS) {
                const uint4 v = *(const uint4*)(src + (size_t)r * 64);
                *(uint4*)&Xs[r * XSTR + g * 8] = v;
            }
        }
    }
    __syncthreads();

    const int w    = tid >> 6;
    const int l    = tid & 63;
    const int lr   = l & 15;
    const int q8   = (l >> 4) * 8;
    const int wrow = w * 32;

    const uint4* gp = (const uint4*)gsw + l;
    uint4 bn[8];
    #pragma unroll
    for (int f = 0; f < 8; ++f) bn[f] = gp[f * 64];

    f32x4 acc[2][4];
    const f32x4 zero = {0.f, 0.f, 0.f, 0.f};
    #pragma unroll
    for (int mt = 0; mt < 2; ++mt)
        #pragma unroll
        for (int nt = 0; nt < 4; ++nt) acc[mt][nt] = zero;

    #pragma unroll 2
    for (int m = 0; m < TLAG; ++m) {
        bf16x8 bc[8];
        #pragma unroll
        for (int f = 0; f < 8; ++f) bc[f] = __builtin_bit_cast(bf16x8, bn[f]);
        if (m < TLAG - 1) {
            const uint4* gn = gp + (size_t)(m + 1) * 512;
            #pragma unroll
            for (int f = 0; f < 8; ++f) bn[f] = gn[f * 64];
        }

        const int rbase = wrow + lr + (TLAG - 1) - m;
        bf16x8 a[2][2];
        #pragma unroll
        for (int mt = 0; mt < 2; ++mt)
            #pragma unroll
            for (int ks = 0; ks < 2; ++ks)
                a[mt][ks] = *(const bf16x8*)&Xs[(rbase + mt * 16) * XSTR + ks * 32 + q8];

        #pragma unroll
        for (int ks = 0; ks < 2; ++ks)
            #pragma unroll
            for (int mt = 0; mt < 2; ++mt)
                #pragma unroll
                for (int nt = 0; nt < 4; ++nt)
                    acc[mt][nt] = __builtin_amdgcn_mfma_f32_16x16x32_bf16(
                        a[mt][ks], bc[ks * 4 + nt], acc[mt][nt], 0, 0, 0);
    }

    // Epilogue: C/D layout col = lane&15 (out-feature), row = (lane>>4)*4+reg (time).
    const int rr = (l >> 4) * 4;
    #pragma unroll
    for (int mt = 0; mt < 2; ++mt) {
        #pragma unroll
        for (int nt = 0; nt < 4; ++nt) {
            const int t = t0 + wrow + mt * 16 + rr;
            const int o = nt * 16 + lr;
            float* yp = y + ((size_t)b * SEQ + t) * 64 + o;
            #pragma unroll
            for (int r = 0; r < 4; ++r) yp[(size_t)r * 64] = acc[mt][nt][r];
        }
    }
}

// ---------------------------------------------------------------------------
// Workspace layout (bytes, 16-aligned):
//   0         xbf    8,650,752   (16 x 4224 x 64 bf16)
//   8650752   Ap0      524,288   (A^h row-major, ping)
//   9175040   Ap1      524,288   (pong)
//   9699328   ApT0     524,288   (A^h transposed, ping)
//  10223616   ApT1     524,288   (pong)
//  10747904   BT        65,536   (B^T [64][512])
//  10813440   Wall   8,388,608   ([128*64][512]: row m*64+o = W_m[o][:] = (C A^m)[o][:])
//  19202048   Gtmp   1,048,576   ([128*64][64]: row m*64+o, col i = G_m[o][i])
//  20250624   Gsw    1,048,576   (B-fragment-swizzled conv kernels)
//  total: 21,299,200
// ---------------------------------------------------------------------------
extern "C" void kernel_launch(void* const* d_in, const int* in_sizes, int n_in,
                              void* d_out, int out_size, void* d_ws, size_t ws_size,
                              hipStream_t stream)
{
    const float* x = (const float*)d_in[0];
    const float* A = (const float*)d_in[1];
    const float* B = (const float*)d_in[2];
    const float* C = (const float*)d_in[3];
    const float* D = (const float*)d_in[4];
    float* y = (float*)d_out;

    char* w = (char*)d_ws;
    u16* xbf  = (u16*)(w + 0);
    u16* Ap0  = (u16*)(w + 8650752);
    u16* Ap1  = (u16*)(w + 9175040);
    u16* ApT0 = (u16*)(w + 9699328);
    u16* ApT1 = (u16*)(w + 10223616);
    u16* BT   = (u16*)(w + 10747904);
    u16* Wall = (u16*)(w + 10813440);
    u16* Gtmp = (u16*)(w + 19202048);
    u16* Gsw  = (u16*)(w + 20250624);

    void* args[] = { (void*)&x, (void*)&A, (void*)&B, (void*)&C, (void*)&D,
                     (void*)&xbf, (void*)&Ap0, (void*)&Ap1, (void*)&ApT0, (void*)&ApT1,
                     (void*)&BT, (void*)&Wall, (void*)&Gtmp, (void*)&Gsw };
    hipLaunchCooperativeKernel((void*)chain_kernel, dim3(512), dim3(256), args, 0, stream);

    conv_kernel<<<dim3(SEQ / CTILE, BATCH), 256, 0, stream>>>(xbf, Gsw, y);
}

// Round 2
// 907.792 us; speedup vs baseline: 1.2856x; 1.2856x over previous
//
#include <hip/hip_runtime.h>
#include <cstdint>
#include <cstddef>

// Problem constants (fixed by reference).
#define BATCH 16
#define SEQ   4096
#define NS    512
#define TLAG  128            // truncation: ||A^128|| ~ 1e-5 -> error ~1e-4 << bf16 noise
#define PADR  128            // zero left-pad rows in padded x buffer
#define PS    (SEQ + PADR)   // 4224 padded rows per batch
#define CTILE 128            // conv time-tile rows per block
#define XROWS (CTILE + TLAG - 1)   // 255 staged rows
#define XSTR  72             // LDS row stride in u16 (144 B = 9*16B)

typedef unsigned short u16;
typedef unsigned int   u32;
typedef short bf16x8 __attribute__((ext_vector_type(8)));   // 8 bf16 = 4 VGPRs
typedef float f32x4  __attribute__((ext_vector_type(4)));   // MFMA accumulator

__device__ __forceinline__ u16 f2bf(float f) {
    u32 u = __builtin_bit_cast(u32, f);
    return (u16)((u + 0x7FFFu + ((u >> 16) & 1u)) >> 16);   // RNE
}
__device__ __forceinline__ float bf2f(u16 h) {
    return __builtin_bit_cast(float, (u32)h << 16);
}

// ---------------------------------------------------------------------------
// prep_all: one launch for all input conversion (round-0 version, unchanged).
// Also zero-inits the grid-barrier counter used by wchain_kernel.
// ---------------------------------------------------------------------------
__global__ __launch_bounds__(256) void prep_all(const float* __restrict__ x,
                                                const float* __restrict__ A,
                                                const float* __restrict__ B,
                                                const float* __restrict__ C,
                                                u16* __restrict__ xbf,
                                                u16* __restrict__ Ap0,
                                                u16* __restrict__ ApT0,
                                                u16* __restrict__ BT,
                                                u16* __restrict__ Wall,
                                                u32* __restrict__ bar)
{
    const int bid = blockIdx.x;
    if (bid == 4224 && threadIdx.x == 0) bar[0] = 0;   // barrier count init
    if (bid < 4224) {
        const int id = bid * 256 + threadIdx.x;      // 16*4224*16 = 1,081,344
        const int b   = id / (PS * 16);
        const int rem = id - b * (PS * 16);
        const int p   = rem >> 4;
        const int g   = id & 15;
        ushort4 o;
        if (p < PADR) {
            o.x = 0; o.y = 0; o.z = 0; o.w = 0;
        } else {
            const float4 v = *(const float4*)(x + ((size_t)b * SEQ + (p - PADR)) * 64 + g * 4);
            o.x = f2bf(v.x); o.y = f2bf(v.y); o.z = f2bf(v.z); o.w = f2bf(v.w);
        }
        *(ushort4*)(xbf + ((size_t)b * PS + p) * 64 + g * 4) = o;
    } else {
        const int id = (bid - 4224) * 256 + threadIdx.x;   // 327,680 total
        if (id < 262144) {                                 // A: 512x512
            const int r = id >> 9, c = id & 511;
            const u16 v = f2bf(A[id]);
            Ap0[id] = v;
            ApT0[(size_t)c * 512 + r] = v;
            (void)r;
        } else if (id < 262144 + 32768) {                  // B: 512x64 -> B^T
            const int i = id - 262144;
            const int k = i >> 6, c = i & 63;
            BT[(size_t)c * 512 + k] = f2bf(B[i]);
        } else if (id < 262144 + 65536) {                  // C: 64x512 -> W_0
            const int i = id - 262144 - 32768;
            Wall[i] = f2bf(C[i]);
        }
    }
}

// ---------------------------------------------------------------------------
// gemm_tile64: one 64(M)x64(N) output tile, K = 512, bf16 in / fp32 acc /
// bf16 out. Layouts verified previously. block = 256 (4 waves x 16 rows).
// ---------------------------------------------------------------------------
__device__ __forceinline__ void gemm_tile64(const u16* __restrict__ apM, int lda,
                                            const u16* __restrict__ bT, int ldbt, int n0,
                                            u16* __restrict__ oRM, int ldo,
                                            u16* __restrict__ oT, int ldoT, int rowT)
{
    const int tid = threadIdx.x;
    const int w = tid >> 6, l = tid & 63;
    const int lr = l & 15, q8 = (l >> 4) * 8;

    const u16* ap  = apM + (size_t)(w * 16 + lr) * lda + q8;
    const u16* bp0 = bT  + (size_t)(n0 + lr) * ldbt + q8;

    f32x4 acc[4];
    const f32x4 zero = {0.f, 0.f, 0.f, 0.f};
    #pragma unroll
    for (int nt = 0; nt < 4; ++nt) acc[nt] = zero;

    #pragma unroll 4
    for (int ks = 0; ks < 16; ++ks) {
        const bf16x8 a = *(const bf16x8*)(ap + ks * 32);
        #pragma unroll
        for (int nt = 0; nt < 4; ++nt) {
            const bf16x8 bfr = *(const bf16x8*)(bp0 + (size_t)nt * 16 * ldbt + ks * 32);
            acc[nt] = __builtin_amdgcn_mfma_f32_16x16x32_bf16(a, bfr, acc[nt], 0, 0, 0);
        }
    }

    const int rr = (l >> 4) * 4;    // C/D: row = (lane>>4)*4 + reg, col = lane&15
    #pragma unroll
    for (int nt = 0; nt < 4; ++nt) {
        const int col = n0 + nt * 16 + lr;
        if (oRM) {
            #pragma unroll
            for (int r = 0; r < 4; ++r)
                oRM[(size_t)(w * 16 + rr + r) * ldo + col] = f2bf(acc[nt][r]);
        }
        if (oT) {
            ushort4 pk;
            pk.x = f2bf(acc[nt][0]); pk.y = f2bf(acc[nt][1]);
            pk.z = f2bf(acc[nt][2]); pk.w = f2bf(acc[nt][3]);
            *(ushort4*)(oT + (size_t)col * ldoT + rowT + w * 16 + rr) = pk;
        }
    }
}

// ---------------------------------------------------------------------------
// gridbar: custom sense-counter grid barrier. NOT cooperative-groups (that
// cost ~130us/sync in round 1 -- sleep-backoff spin in the CG runtime).
// grid = 256 blocks <= 256 CUs -> co-residency structurally guaranteed.
// __threadfence() release/acquire on both sides gives cross-XCD L2
// visibility (same fence pattern that passed numerically in round 1).
// bar[0] = arrival count (self-cleaning: last block resets it before the
// generation bump, so state is 0 at kernel exit). bar[1] = generation.
// ---------------------------------------------------------------------------
__device__ __forceinline__ void gridbar(u32* __restrict__ bar)
{
    __threadfence();
    __syncthreads();
    if (threadIdx.x == 0) {
        u32* cnt = bar;
        u32* gen = bar + 1;
        const u32 g = __hip_atomic_load(gen, __ATOMIC_RELAXED, __HIP_MEMORY_SCOPE_AGENT);
        const u32 nb = gridDim.x * gridDim.y * gridDim.z;
        if (__hip_atomic_fetch_add(cnt, 1u, __ATOMIC_ACQ_REL, __HIP_MEMORY_SCOPE_AGENT) == nb - 1u) {
            __hip_atomic_store(cnt, 0u, __ATOMIC_RELAXED, __HIP_MEMORY_SCOPE_AGENT);
            __hip_atomic_store(gen, g + 1u, __ATOMIC_RELEASE, __HIP_MEMORY_SCOPE_AGENT);
        } else {
            while (__hip_atomic_load(gen, __ATOMIC_ACQUIRE, __HIP_MEMORY_SCOPE_AGENT) == g) {
                __builtin_amdgcn_s_sleep(2);   // ~128 cycles per poll
            }
        }
    }
    __syncthreads();
    __threadfence();
}

// ---------------------------------------------------------------------------
// wchain_kernel: ONE persistent launch (256 blocks, 1/CU) for the W-chain:
//   7 doubling levels (expansion + squaring), Gtmp = W@B, repack -> Gsw.
// 8 custom grid barriers replace 9 dependent stream launches. Identical
// arithmetic / operand order to the round-0 level_kernel chain -> output
// must be bit-identical (absmax 0.078125 exactly).
// ---------------------------------------------------------------------------
__global__ __launch_bounds__(256, 1) void wchain_kernel(const float* __restrict__ D,
                                                        u16* __restrict__ Ap0,
                                                        u16* __restrict__ Ap1,
                                                        u16* __restrict__ ApT0,
                                                        u16* __restrict__ ApT1,
                                                        const u16* __restrict__ BT,
                                                        u16* __restrict__ Wall,
                                                        u16* __restrict__ Gtmp,
                                                        u16* __restrict__ Gsw,
                                                        u32* __restrict__ bar)
{
    const int tid = threadIdx.x;
    const int nb  = gridDim.x;

    // ---- 7 doubling levels ----
    u16* ApCur  = Ap0;  u16* ApTCur  = ApT0;
    u16* ApNext = Ap1;  u16* ApTNext = ApT1;
    int h = 1;
    while (h < TLAG) {
        const int nexp  = (h < TLAG - h) ? h : (TLAG - h);
        const int do_sq = (2 * h < TLAG) ? 1 : 0;
        const int ntiles = 8 * (nexp + (do_sq ? 8 : 0));
        for (int t = blockIdx.x; t < ntiles; t += nb) {
            const int n0 = (t & 7) * 64;
            const int by = t >> 3;
            if (by < nexp) {
                gemm_tile64(Wall + (size_t)by * 64 * NS, NS, ApTCur, NS, n0,
                            Wall + (size_t)(h + by) * 64 * NS, NS, nullptr, 0, 0);
            } else {
                const int j = by - nexp;
                gemm_tile64(ApCur + (size_t)j * 64 * NS, NS, ApTCur, NS, n0,
                            ApNext + (size_t)j * 64 * NS, NS, ApTNext, NS, j * 64);
            }
        }
        if (do_sq) {
            u16* tmp;
            tmp = ApCur;  ApCur  = ApNext;  ApNext  = tmp;
            tmp = ApTCur; ApTCur = ApTNext; ApTNext = tmp;
        }
        h += nexp;
        gridbar(bar);
    }

    // ---- Gtmp[m*64+o][i] = (W_m @ B)[o][i] ----
    for (int t = blockIdx.x; t < TLAG; t += nb) {
        gemm_tile64(Wall + (size_t)t * 64 * NS, NS, BT, NS, 0,
                    Gtmp + (size_t)t * 64 * 64, 64, nullptr, 0, 0);
    }
    gridbar(bar);

    // ---- repack Gtmp -> Gsw in exact B-fragment order (fold D into lag 0) ----
    for (int id = blockIdx.x * 256 + tid; id < 65536; id += nb * 256) {
        const int l  = id & 63;
        const int fi = id >> 6;
        const int m  = fi >> 3;
        const int ks = (fi >> 2) & 1;
        const int nt = fi & 3;
        const int o  = nt * 16 + (l & 15);
        const int q8 = (l >> 4) * 8;

        u16 v[8];
        #pragma unroll
        for (int j = 0; j < 8; ++j) {
            const int i = ks * 32 + q8 + j;
            u16 g = Gtmp[(size_t)(m * 64 + o) * 64 + i];
            if (m == 0) g = f2bf(bf2f(g) + D[o * 64 + i]);
            v[j] = g;
        }
        ushort4* dst = (ushort4*)(Gsw + (size_t)id * 8);
        ushort4 p0; p0.x = v[0]; p0.y = v[1]; p0.z = v[2]; p0.w = v[3];
        ushort4 p1; p1.x = v[4]; p1.y = v[5]; p1.z = v[6]; p1.w = v[7];
        dst[0] = p0; dst[1] = p1;
    }
}

// ---------------------------------------------------------------------------
// conv_kernel: y[b, t0+tau, o] = sum_{m<128} sum_i G_m[o][i] x[t0+tau-m][i]
// Round-2 change: 512 threads = 8 waves x 16 rows (was 4 waves x 32 rows).
// Same grid (32,16) = 512 blocks, 2 blocks/CU -> now 4 waves/SIMD (was 2)
// for latency hiding; MfmaUtil 37% was dependency-stall-bound at 2 w/SIMD.
// Accumulation order per output element unchanged -> bit-identical y.
// ---------------------------------------------------------------------------
__global__ __launch_bounds__(512, 4) void conv_kernel(const u16* __restrict__ xbf,
                                                      const u16* __restrict__ gsw,
                                                      float* __restrict__ y)
{
    __shared__ u16 Xs[XROWS * XSTR];   // 36,720 B; x2 blocks/CU = 73,440 < 160K

    const int tid = threadIdx.x;
    const int b  = blockIdx.y;
    const int t0 = blockIdx.x * CTILE;

    // Stage padded rows [t0+1 .. t0+255] (= times t0-127 .. t0+127) into LDS.
    {
        const int g = tid & 7;
        int r = tid >> 3;                    // 0..63
        const u16* src = xbf + ((size_t)b * PS + t0 + 1) * 64 + g * 8;
        #pragma unroll
        for (int it = 0; it < 4; ++it, r += 64) {
            if (r < XROWS) {
                const uint4 v = *(const uint4*)(src + (size_t)r * 64);
                *(uint4*)&Xs[r * XSTR + g * 8] = v;
            }
        }
    }
    __syncthreads();

    const int w    = tid >> 6;         // 0..7
    const int l    = tid & 63;
    const int lr   = l & 15;
    const int q8   = (l >> 4) * 8;
    const int wrow = w * 16;           // 16 time-rows per wave

    const uint4* gp = (const uint4*)gsw + l;
    uint4 bn[8];
    #pragma unroll
    for (int f = 0; f < 8; ++f) bn[f] = gp[f * 64];

    f32x4 acc[4];
    const f32x4 zero = {0.f, 0.f, 0.f, 0.f};
    #pragma unroll
    for (int nt = 0; nt < 4; ++nt) acc[nt] = zero;

    #pragma unroll 2
    for (int m = 0; m < TLAG; ++m) {
        bf16x8 bc[8];
        #pragma unroll
        for (int f = 0; f < 8; ++f) bc[f] = __builtin_bit_cast(bf16x8, bn[f]);
        if (m < TLAG - 1) {
            const uint4* gn = gp + (size_t)(m + 1) * 512;
            #pragma unroll
            for (int f = 0; f < 8; ++f) bn[f] = gn[f * 64];
        }

        const int rbase = wrow + lr + (TLAG - 1) - m;
        bf16x8 a[2];
        #pragma unroll
        for (int ks = 0; ks < 2; ++ks)
            a[ks] = *(const bf16x8*)&Xs[rbase * XSTR + ks * 32 + q8];

        #pragma unroll
        for (int ks = 0; ks < 2; ++ks)
            #pragma unroll
            for (int nt = 0; nt < 4; ++nt)
                acc[nt] = __builtin_amdgcn_mfma_f32_16x16x32_bf16(
                    a[ks], bc[ks * 4 + nt], acc[nt], 0, 0, 0);
    }

    // Epilogue: C/D layout col = lane&15 (out-feature), row = (lane>>4)*4+reg (time).
    const int rr = (l >> 4) * 4;
    #pragma unroll
    for (int nt = 0; nt < 4; ++nt) {
        const int t = t0 + wrow + rr;
        const int o = nt * 16 + lr;
        float* yp = y + ((size_t)b * SEQ + t) * 64 + o;
        #pragma unroll
        for (int r = 0; r < 4; ++r) yp[(size_t)r * 64] = acc[nt][r];
    }
}

// ---------------------------------------------------------------------------
// Workspace layout (bytes, 16-aligned):
//   0         xbf    8,650,752   (16 x 4224 x 64 bf16)
//   8650752   Ap0      524,288   (A^h row-major, ping)
//   9175040   Ap1      524,288   (pong)
//   9699328   ApT0     524,288   (A^h transposed, ping)
//  10223616   ApT1     524,288   (pong)
//  10747904   BT        65,536   (B^T [64][512])
//  10813440   Wall   8,388,608   ([128*64][512]: row m*64+o = W_m[o][:] = (C A^m)[o][:])
//  19202048   Gtmp   1,048,576   ([128*64][64]: row m*64+o, col i = G_m[o][i])
//  20250624   Gsw    1,048,576   (B-fragment-swizzled conv kernels)
//  21299200   bar            8   (grid barrier: count, generation)
//  total: 21,299,208
// ---------------------------------------------------------------------------
extern "C" void kernel_launch(void* const* d_in, const int* in_sizes, int n_in,
                              void* d_out, int out_size, void* d_ws, size_t ws_size,
                              hipStream_t stream)
{
    const float* x = (const float*)d_in[0];
    const float* A = (const float*)d_in[1];
    const float* B = (const float*)d_in[2];
    const float* C = (const float*)d_in[3];
    const float* D = (const float*)d_in[4];
    float* y = (float*)d_out;

    char* w = (char*)d_ws;
    u16* xbf  = (u16*)(w + 0);
    u16* Ap0  = (u16*)(w + 8650752);
    u16* Ap1  = (u16*)(w + 9175040);
    u16* ApT0 = (u16*)(w + 9699328);
    u16* ApT1 = (u16*)(w + 10223616);
    u16* BT   = (u16*)(w + 10747904);
    u16* Wall = (u16*)(w + 10813440);
    u16* Gtmp = (u16*)(w + 19202048);
    u16* Gsw  = (u16*)(w + 20250624);
    u32* bar  = (u32*)(w + 21299200);

    prep_all<<<5504, 256, 0, stream>>>(x, A, B, C, xbf, Ap0, ApT0, BT, Wall, bar);
    wchain_kernel<<<256, 256, 0, stream>>>(D, Ap0, Ap1, ApT0, ApT1, BT, Wall, Gtmp, Gsw, bar);
    conv_kernel<<<dim3(SEQ / CTILE, BATCH), 512, 0, stream>>>(xbf, Gsw, y);
}

// Round 3
// 348.020 us; speedup vs baseline: 3.3535x; 2.6084x over previous
//
#include <hip/hip_runtime.h>
#include <cstdint>
#include <cstddef>

// Problem constants (fixed by reference).
#define BATCH 16
#define SEQ   4096
#define NS    512
#define TLAG  128            // truncation: ||A^128|| ~ 1e-5 -> error ~1e-4 << bf16 noise
#define PADR  128            // zero left-pad rows in padded x buffer
#define PS    (SEQ + PADR)   // 4224 padded rows per batch
#define CTILE 128            // conv time-tile rows per block
#define XROWS (CTILE + TLAG - 1)   // 255 staged rows
#define XSTR  72             // LDS row stride in u16 (144 B = 9*16B)
#define GB    128            // blocks per chain group (2 groups x 128 = 256 blocks)

typedef unsigned short u16;
typedef unsigned int   u32;
typedef unsigned long long u64;
typedef short bf16x8 __attribute__((ext_vector_type(8)));   // 8 bf16 = 4 VGPRs
typedef float f32x4  __attribute__((ext_vector_type(4)));   // MFMA accumulator

__device__ __forceinline__ u16 f2bf(float f) {
    u32 u = __builtin_bit_cast(u32, f);
    return (u16)((u + 0x7FFFu + ((u >> 16) & 1u)) >> 16);   // RNE
}
__device__ __forceinline__ float bf2f(u16 h) {
    return __builtin_bit_cast(float, (u32)h << 16);
}

// Write-through 8B store: RELAXED+AGENT atomic store compiles to a cache-
// bypassing (sc0 sc1) global_store -> globally visible once vmcnt drains.
// This replaces device-scope fences (which flush the whole XCD L2, ~90us/
// barrier measured in round 2).
__device__ __forceinline__ void wt_store(u16* p, ushort4 v) {
    __hip_atomic_store((u64*)p, __builtin_bit_cast(u64, v),
                       __ATOMIC_RELAXED, __HIP_MEMORY_SCOPE_AGENT);
}

// ---------------------------------------------------------------------------
// prep_all: one launch for all input conversion.
//  blocks [0,4224):    x fp32 -> xbf bf16 (128 zero rows prepended per batch)
//  blocks [4224,5888): A -> Arm + At (transposed); B -> BT; C -> W_0 of BOTH
//                      group Wall copies; zero the 64 barrier flags.
// ---------------------------------------------------------------------------
__global__ __launch_bounds__(256) void prep_all(const float* __restrict__ x,
                                                const float* __restrict__ A,
                                                const float* __restrict__ B,
                                                const float* __restrict__ C,
                                                u16* __restrict__ xbf,
                                                u16* __restrict__ Arm,
                                                u16* __restrict__ At,
                                                u16* __restrict__ BT,
                                                u16* __restrict__ Wall0,
                                                u16* __restrict__ Wall1,
                                                u32* __restrict__ flg)
{
    const int bid = blockIdx.x;
    if (bid == 4224 && threadIdx.x < 64) flg[threadIdx.x] = 0;   // fresh flags each replay
    if (bid < 4224) {
        const int id = bid * 256 + threadIdx.x;      // 16*4224*16 = 1,081,344
        const int b   = id / (PS * 16);
        const int rem = id - b * (PS * 16);
        const int p   = rem >> 4;
        const int g   = id & 15;
        ushort4 o;
        if (p < PADR) {
            o.x = 0; o.y = 0; o.z = 0; o.w = 0;
        } else {
            const float4 v = *(const float4*)(x + ((size_t)b * SEQ + (p - PADR)) * 64 + g * 4);
            o.x = f2bf(v.x); o.y = f2bf(v.y); o.z = f2bf(v.z); o.w = f2bf(v.w);
        }
        *(ushort4*)(xbf + ((size_t)b * PS + p) * 64 + g * 4) = o;
    } else {
        const int id = (bid - 4224) * 256 + threadIdx.x;   // 425,984 total
        if (id < 262144) {                                 // A: 512x512
            const int r = id >> 9, c = id & 511;
            const u16 v = f2bf(A[id]);
            Arm[id] = v;
            At[(size_t)c * 512 + r] = v;
            (void)r;
        } else if (id < 262144 + 32768) {                  // B: 512x64 -> B^T
            const int i = id - 262144;
            const int k = i >> 6, c = i & 63;
            BT[(size_t)c * 512 + k] = f2bf(B[i]);
        } else if (id < 262144 + 32768 + 131072) {         // C -> W_0 (both groups)
            const int i  = id - 262144 - 32768;
            const int gg = i >> 16;
            const int ii = i & 65535;
            const u16 v = f2bf(C[ii]);
            if (gg == 0) Wall0[ii] = v; else Wall1[ii] = v;
        }
    }
}

// ---------------------------------------------------------------------------
// gbar: fence-free per-group barrier. Relaxed agent atomics (execute at the
// coherent point, bypass non-coherent caches); __syncthreads() drains
// vmcnt(0) so all prior wt_stores are globally visible before arrival.
// One fresh counter per (group, level) -> no generation logic, no reuse.
// ---------------------------------------------------------------------------
__device__ __forceinline__ void gbar(u32* __restrict__ f)
{
    __syncthreads();
    if (threadIdx.x == 0) {
        __hip_atomic_fetch_add(f, 1u, __ATOMIC_RELAXED, __HIP_MEMORY_SCOPE_AGENT);
        while (__hip_atomic_load(f, __ATOMIC_RELAXED, __HIP_MEMORY_SCOPE_AGENT) < (u32)GB)
            __builtin_amdgcn_s_sleep(4);
    }
    __syncthreads();
}

// ---------------------------------------------------------------------------
// gemm_wt: one 64x64 output tile, K=512 (all operands 512-wide), bf16 in /
// fp32 acc / bf16 out. Same verified core as previous rounds. Outputs:
//  - oT: transposed out via 8B wt stores (fragment rows are contiguous).
//  - oRM: row-major out via LDS bounce (fragment cols aren't contiguous ->
//         stage 64x64 tile in LDS, re-read row-wise, 8B wt stores).
// block = 256 (4 waves x 16 rows).
// ---------------------------------------------------------------------------
__device__ __forceinline__ void gemm_wt(const u16* __restrict__ apM,
                                        const u16* __restrict__ bT, int n0,
                                        u16* __restrict__ oRM,
                                        u16* __restrict__ oT, int rowT,
                                        u16* __restrict__ lds)
{
    const int tid = threadIdx.x;
    const int w = tid >> 6, l = tid & 63;
    const int lr = l & 15, q8 = (l >> 4) * 8;

    const u16* ap  = apM + (size_t)(w * 16 + lr) * NS + q8;
    const u16* bp0 = bT  + (size_t)(n0 + lr) * NS + q8;

    f32x4 acc[4];
    const f32x4 zero = {0.f, 0.f, 0.f, 0.f};
    #pragma unroll
    for (int nt = 0; nt < 4; ++nt) acc[nt] = zero;

    #pragma unroll 4
    for (int ks = 0; ks < 16; ++ks) {
        const bf16x8 a = *(const bf16x8*)(ap + ks * 32);
        #pragma unroll
        for (int nt = 0; nt < 4; ++nt) {
            const bf16x8 bfr = *(const bf16x8*)(bp0 + (size_t)nt * 16 * NS + ks * 32);
            acc[nt] = __builtin_amdgcn_mfma_f32_16x16x32_bf16(a, bfr, acc[nt], 0, 0, 0);
        }
    }

    const int rr = (l >> 4) * 4;    // C/D: row = (lane>>4)*4 + reg, col = lane&15
    if (oT) {
        #pragma unroll
        for (int nt = 0; nt < 4; ++nt) {
            const int col = n0 + nt * 16 + lr;
            ushort4 pk;
            pk.x = f2bf(acc[nt][0]); pk.y = f2bf(acc[nt][1]);
            pk.z = f2bf(acc[nt][2]); pk.w = f2bf(acc[nt][3]);
            wt_store(oT + (size_t)col * NS + rowT + w * 16 + rr, pk);
        }
    }
    if (oRM) {
        __syncthreads();   // protect LDS from previous tile's readers
        #pragma unroll
        for (int nt = 0; nt < 4; ++nt)
            #pragma unroll
            for (int r = 0; r < 4; ++r)
                lds[(w * 16 + rr + r) * 72 + nt * 16 + lr] = f2bf(acc[nt][r]);
        __syncthreads();
        const int r  = tid >> 2;             // 0..63
        const int c0 = (tid & 3) * 16;       // 0,16,32,48
        #pragma unroll
        for (int k = 0; k < 4; ++k) {
            const ushort4 q = *(const ushort4*)&lds[r * 72 + c0 + k * 4];
            wt_store(oRM + (size_t)r * NS + n0 + c0 + k * 4, q);
        }
    }
}

// ---------------------------------------------------------------------------
// g_tile: G_m = W_m @ B, written DIRECTLY in conv's B-fragment-swizzled order
// via LDS bounce (fuses round-0's gfinal + repack; identical f2bf points ->
// bit-identical). D folded into lag 0.
// ---------------------------------------------------------------------------
__device__ __forceinline__ void g_tile(const u16* __restrict__ apW,
                                       const u16* __restrict__ BT, int m,
                                       const float* __restrict__ D,
                                       u16* __restrict__ Gsw,
                                       u16* __restrict__ lds)
{
    const int tid = threadIdx.x;
    const int w = tid >> 6, l = tid & 63;
    const int lr = l & 15, q8 = (l >> 4) * 8;

    const u16* ap  = apW + (size_t)(w * 16 + lr) * NS + q8;
    const u16* bp0 = BT  + (size_t)lr * NS + q8;

    f32x4 acc[4];
    const f32x4 zero = {0.f, 0.f, 0.f, 0.f};
    #pragma unroll
    for (int nt = 0; nt < 4; ++nt) acc[nt] = zero;

    #pragma unroll 4
    for (int ks = 0; ks < 16; ++ks) {
        const bf16x8 a = *(const bf16x8*)(ap + ks * 32);
        #pragma unroll
        for (int nt = 0; nt < 4; ++nt) {
            const bf16x8 bfr = *(const bf16x8*)(bp0 + (size_t)nt * 16 * NS + ks * 32);
            acc[nt] = __builtin_amdgcn_mfma_f32_16x16x32_bf16(a, bfr, acc[nt], 0, 0, 0);
        }
    }

    const int rr = (l >> 4) * 4;
    __syncthreads();
    #pragma unroll
    for (int nt = 0; nt < 4; ++nt)       // lds[o][i] = f2bf(G_m[o][i])
        #pragma unroll
        for (int r = 0; r < 4; ++r)
            lds[(w * 16 + rr + r) * 72 + nt * 16 + lr] = f2bf(acc[nt][r]);
    __syncthreads();

    const int f = tid >> 6;              // 0..3
    #pragma unroll
    for (int f2 = 0; f2 < 8; f2 += 4) {  // fragments f and f+4
        const int fi = f2 + f;
        const int ks = fi >> 2, nt = fi & 3;
        const int o  = nt * 16 + (l & 15);
        const int i0 = ks * 32 + (l >> 4) * 8;
        u16 v[8];
        #pragma unroll
        for (int j = 0; j < 8; ++j) {
            u16 gv = lds[o * 72 + i0 + j];
            if (m == 0) gv = f2bf(bf2f(gv) + D[o * 64 + i0 + j]);
            v[j] = gv;
        }
        ushort4 p0; p0.x = v[0]; p0.y = v[1]; p0.z = v[2]; p0.w = v[3];
        ushort4 p1; p1.x = v[4]; p1.y = v[5]; p1.z = v[6]; p1.w = v[7];
        u16* dst = Gsw + ((size_t)(m * 8 + fi) * 64 + l) * 8;
        wt_store(dst + 0, p0);
        wt_store(dst + 4, p1);
    }
}

// ---------------------------------------------------------------------------
// chain2: ONE plain launch (256 blocks = 2 groups x 128) for the whole
// W-chain + G + repack. Each group redundantly computes the squaring chain
// S_k = A^{2^k} and W rows [0,64); group g owns W rows [64+32g,96+32g) and
// G lags {[32g,32g+32)} U {[64+32g,64+32g+32)}. All cross-block data flows
// through wt stores (coherent point); per-group fence-free barriers; every
// buffer written once then read (no read-before-write -> no stale caches).
// Math/association identical to round-0 verified chain -> bit-identical y.
// ---------------------------------------------------------------------------
__global__ __launch_bounds__(256, 1) void chain2(const float* __restrict__ D,
                                                 const u16* __restrict__ Arm,
                                                 const u16* __restrict__ At,
                                                 const u16* __restrict__ BT,
                                                 u16* __restrict__ S0,     // 2 groups x 6 powers x (rm,t)
                                                 u16* __restrict__ Wall0,  // 2 groups x [128*64][512]
                                                 u16* __restrict__ Gsw,
                                                 u32* __restrict__ flg)
{
    __shared__ u16 lds[64 * 72];   // 9,216 B bounce buffer

    const int g    = blockIdx.x >> 7;          // group 0/1
    const int rank = blockIdx.x & (GB - 1);    // 0..127
    u16* Sb = S0 + (size_t)g * 3145728;        // 6 * 524,288 u16 per group
    u16* Wg = Wall0 + (size_t)g * 4194304;     // 128*64*512 u16 per group
    u32* fg = flg + g * 16;

    // ---- levels 0..5: h = 1<<lvl; W[h..2h) = W[0..h) * A^h; S_{lvl+1} = S_lvl^2 ----
    #pragma unroll 1
    for (int lvl = 0; lvl < 6; ++lvl) {
        const int h = 1 << lvl;
        const u16* aSq = (lvl == 0) ? Arm : (Sb + (size_t)(lvl - 1) * 524288);
        const u16* bTh = (lvl == 0) ? At  : (Sb + (size_t)(lvl - 1) * 524288 + 262144);
        u16* SnRM = Sb + (size_t)lvl * 524288;            // S_{lvl+1} row-major
        u16* SnT  = SnRM + 262144;                        // S_{lvl+1} transposed
        const int nexp8  = h * 8;
        const int ntiles = nexp8 + 64;
        for (int t = rank; t < ntiles; t += GB) {
            if (t < nexp8) {
                const int by = t >> 3, n0 = (t & 7) * 64;
                gemm_wt(Wg + (size_t)by * 64 * NS, bTh, n0,
                        Wg + (size_t)(h + by) * 64 * NS, nullptr, 0, lds);
            } else {
                const int tt = t - nexp8, mr = tt >> 3, n0 = (tt & 7) * 64;
                gemm_wt(aSq + (size_t)mr * 64 * NS, bTh, n0,
                        (lvl + 1 < 6) ? (SnRM + (size_t)mr * 64 * NS) : nullptr,
                        SnT, mr * 64, lds);
            }
        }
        gbar(&fg[lvl]);
    }

    // ---- level 6 (h=64): W[64+q] = W[q] * S6, q in [32g, 32g+32) ----
    {
        const u16* S6t = Sb + (size_t)5 * 524288 + 262144;
        for (int t = rank; t < 256; t += GB) {
            const int by = 32 * g + (t >> 3), n0 = (t & 7) * 64;
            gemm_wt(Wg + (size_t)by * 64 * NS, S6t, n0,
                    Wg + (size_t)(64 + by) * 64 * NS, nullptr, 0, lds);
        }
        gbar(&fg[6]);
    }

    // ---- G level: G_m = W_m @ B, swizzled + D-fold, 64 lags per group ----
    if (rank < 64) {
        const int m = (rank < 32) ? (32 * g + rank) : (64 + 32 * g + rank - 32);
        g_tile(Wg + (size_t)m * 64 * NS, BT, m, D, Gsw, lds);
    }
}

// ---------------------------------------------------------------------------
// conv_kernel: EXACT round-0 version (measured 78.5 us, MfmaUtil 37%).
// ---------------------------------------------------------------------------
__global__ __launch_bounds__(256, 2) void conv_kernel(const u16* __restrict__ xbf,
                                                      const u16* __restrict__ gsw,
                                                      float* __restrict__ y)
{
    __shared__ u16 Xs[XROWS * XSTR];   // 36,720 B -> >=2 blocks/CU

    const int tid = threadIdx.x;
    const int b  = blockIdx.y;
    const int t0 = blockIdx.x * CTILE;

    {
        const int g = tid & 7;
        int r = tid >> 3;
        const u16* src = xbf + ((size_t)b * PS + t0 + 1) * 64 + g * 8;
        #pragma unroll
        for (int it = 0; it < 8; ++it, r += 32) {
            if (r < XROWS) {
                const uint4 v = *(const uint4*)(src + (size_t)r * 64);
                *(uint4*)&Xs[r * XSTR + g * 8] = v;
            }
        }
    }
    __syncthreads();

    const int w    = tid >> 6;
    const int l    = tid & 63;
    const int lr   = l & 15;
    const int q8   = (l >> 4) * 8;
    const int wrow = w * 32;

    const uint4* gp = (const uint4*)gsw + l;
    uint4 bn[8];
    #pragma unroll
    for (int f = 0; f < 8; ++f) bn[f] = gp[f * 64];

    f32x4 acc[2][4];
    const f32x4 zero = {0.f, 0.f, 0.f, 0.f};
    #pragma unroll
    for (int mt = 0; mt < 2; ++mt)
        #pragma unroll
        for (int nt = 0; nt < 4; ++nt) acc[mt][nt] = zero;

    #pragma unroll 2
    for (int m = 0; m < TLAG; ++m) {
        bf16x8 bc[8];
        #pragma unroll
        for (int f = 0; f < 8; ++f) bc[f] = __builtin_bit_cast(bf16x8, bn[f]);
        if (m < TLAG - 1) {
            const uint4* gn = gp + (size_t)(m + 1) * 512;
            #pragma unroll
            for (int f = 0; f < 8; ++f) bn[f] = gn[f * 64];
        }

        const int rbase = wrow + lr + (TLAG - 1) - m;
        bf16x8 a[2][2];
        #pragma unroll
        for (int mt = 0; mt < 2; ++mt)
            #pragma unroll
            for (int ks = 0; ks < 2; ++ks)
                a[mt][ks] = *(const bf16x8*)&Xs[(rbase + mt * 16) * XSTR + ks * 32 + q8];

        #pragma unroll
        for (int ks = 0; ks < 2; ++ks)
            #pragma unroll
            for (int mt = 0; mt < 2; ++mt)
                #pragma unroll
                for (int nt = 0; nt < 4; ++nt)
                    acc[mt][nt] = __builtin_amdgcn_mfma_f32_16x16x32_bf16(
                        a[mt][ks], bc[ks * 4 + nt], acc[mt][nt], 0, 0, 0);
    }

    const int rr = (l >> 4) * 4;
    #pragma unroll
    for (int mt = 0; mt < 2; ++mt) {
        #pragma unroll
        for (int nt = 0; nt < 4; ++nt) {
            const int t = t0 + wrow + mt * 16 + rr;
            const int o = nt * 16 + lr;
            float* yp = y + ((size_t)b * SEQ + t) * 64 + o;
            #pragma unroll
            for (int r = 0; r < 4; ++r) yp[(size_t)r * 64] = acc[mt][nt][r];
        }
    }
}

// ---------------------------------------------------------------------------
// Workspace layout (bytes, 16-aligned):
//   0          xbf    8,650,752   (16 x 4224 x 64 bf16)
//   8,650,752  Arm      524,288   (A row-major)
//   9,175,040  At       524,288   (A transposed)
//   9,699,328  BT        65,536   (B^T [64][512])
//   9,764,864  S       12,582,912 (2 groups x 6 powers x (rm 512KB + t 512KB))
//  22,347,776  Wall    16,777,216 (2 groups x [128*64][512])
//  39,124,992  Gsw      1,048,576 (B-fragment-swizzled conv kernels)
//  40,173,568  flg            256 (64 u32 barrier counters)
//  total: 40,173,824
// ---------------------------------------------------------------------------
extern "C" void kernel_launch(void* const* d_in, const int* in_sizes, int n_in,
                              void* d_out, int out_size, void* d_ws, size_t ws_size,
                              hipStream_t stream)
{
    const float* x = (const float*)d_in[0];
    const float* A = (const float*)d_in[1];
    const float* B = (const float*)d_in[2];
    const float* C = (const float*)d_in[3];
    const float* D = (const float*)d_in[4];
    float* y = (float*)d_out;

    char* w = (char*)d_ws;
    u16* xbf   = (u16*)(w + 0);
    u16* Arm   = (u16*)(w + 8650752);
    u16* At    = (u16*)(w + 9175040);
    u16* BT    = (u16*)(w + 9699328);
    u16* S0    = (u16*)(w + 9764864);
    u16* Wall0 = (u16*)(w + 22347776);
    u16* Wall1 = Wall0 + 4194304;
    u16* Gsw   = (u16*)(w + 39124992);
    u32* flg   = (u32*)(w + 40173568);

    prep_all<<<5888, 256, 0, stream>>>(x, A, B, C, xbf, Arm, At, BT, Wall0, Wall1, flg);
    chain2<<<256, 256, 0, stream>>>(D, Arm, At, BT, S0, Wall0, Gsw, flg);
    conv_kernel<<<dim3(SEQ / CTILE, BATCH), 256, 0, stream>>>(xbf, Gsw, y);
}

// Round 4
// 236.832 us; speedup vs baseline: 4.9279x; 1.4695x over previous
//
#include <hip/hip_runtime.h>
#include <cstdint>
#include <cstddef>

// Problem constants (fixed by reference).
#define BATCH 16
#define SEQ   4096
#define NS    512
#define TLAG  128            // truncation: ||A^128|| ~ 1e-5 -> error ~1e-4 << bf16 noise
#define PADR  128            // zero left-pad rows in padded x buffer
#define PS    (SEQ + PADR)   // 4224 padded rows per batch
#define CTILE 128            // conv time-tile rows per block
#define XROWS (CTILE + TLAG - 1)   // 255 staged rows
#define XSTR  72             // LDS row stride in u16 (144 B = 9*16B)
#define BLK   32768          // one 64x512 row-block in u16 (64*512)

typedef unsigned short u16;
typedef unsigned int   u32;
typedef short bf16x8 __attribute__((ext_vector_type(8)));   // 8 bf16 = 4 VGPRs
typedef float f32x4  __attribute__((ext_vector_type(4)));   // MFMA accumulator

__device__ __forceinline__ u16 f2bf(float f) {
    u32 u = __builtin_bit_cast(u32, f);
    return (u16)((u + 0x7FFFu + ((u >> 16) & 1u)) >> 16);   // RNE
}
__device__ __forceinline__ float bf2f(u16 h) {
    return __builtin_bit_cast(float, (u32)h << 16);
}

// ---------------------------------------------------------------------------
// prep_all: one launch for all input conversion.
//  blocks [0,4224):    x fp32 -> xbf bf16 (128 zero rows prepended per batch)
//  blocks [4224,5504): A -> Arm + At; B -> BT and Rt[0] (= B^T); C -> L[0].
// ---------------------------------------------------------------------------
__global__ __launch_bounds__(256) void prep_all(const float* __restrict__ x,
                                                const float* __restrict__ A,
                                                const float* __restrict__ B,
                                                const float* __restrict__ C,
                                                u16* __restrict__ xbf,
                                                u16* __restrict__ Arm,
                                                u16* __restrict__ At,
                                                u16* __restrict__ BT,
                                                u16* __restrict__ Rt,
                                                u16* __restrict__ L)
{
    const int bid = blockIdx.x;
    if (bid < 4224) {
        const int id = bid * 256 + threadIdx.x;      // 16*4224*16 = 1,081,344
        const int b   = id / (PS * 16);
        const int rem = id - b * (PS * 16);
        const int p   = rem >> 4;
        const int g   = id & 15;
        ushort4 o;
        if (p < PADR) {
            o.x = 0; o.y = 0; o.z = 0; o.w = 0;
        } else {
            const float4 v = *(const float4*)(x + ((size_t)b * SEQ + (p - PADR)) * 64 + g * 4);
            o.x = f2bf(v.x); o.y = f2bf(v.y); o.z = f2bf(v.z); o.w = f2bf(v.w);
        }
        *(ushort4*)(xbf + ((size_t)b * PS + p) * 64 + g * 4) = o;
    } else {
        const int id = (bid - 4224) * 256 + threadIdx.x;   // 327,680 total
        if (id < 262144) {                                 // A: 512x512
            const int r = id >> 9, c = id & 511;
            const u16 v = f2bf(A[id]);
            Arm[id] = v;
            At[(size_t)c * 512 + r] = v;
            (void)r;
        } else if (id < 262144 + 32768) {                  // B: 512x64 -> B^T (x2)
            const int i = id - 262144;
            const int k = i >> 6, c = i & 63;
            const u16 v = f2bf(B[i]);
            BT[(size_t)c * 512 + k] = v;
            Rt[(size_t)c * 512 + k] = v;                   // R_0^T = B^T
        } else if (id < 262144 + 65536) {                  // C: 64x512 -> L_0
            const int i = id - 262144 - 32768;
            L[i] = f2bf(C[i]);
        }
    }
}

// ---------------------------------------------------------------------------
// gemm_tile: one 64(M)x64(N) output tile, K=512, bf16 in / fp32 acc / bf16
// out. Aop row-major [64][512]; BTop [N_total][512] (operand-B transposed),
// n0 selects the 64-col slice. Outputs: oRM row-major via LDS bounce
// (fragment cols aren't contiguous); oT transposed (absolute row rowT)
// direct 8B stores. Plain cached stores -- kernel boundaries provide
// coherence (round-0 proven model). block = 256 (4 waves x 16 rows).
// ---------------------------------------------------------------------------
__device__ __forceinline__ void gemm_tile(const u16* __restrict__ apM,
                                          const u16* __restrict__ bT, int n0,
                                          u16* __restrict__ oRM,
                                          u16* __restrict__ oT, int rowT,
                                          u16* __restrict__ lds)
{
    const int tid = threadIdx.x;
    const int w = tid >> 6, l = tid & 63;
    const int lr = l & 15, q8 = (l >> 4) * 8;

    const u16* ap  = apM + (size_t)(w * 16 + lr) * NS + q8;
    const u16* bp0 = bT  + (size_t)(n0 + lr) * NS + q8;

    f32x4 acc[4];
    const f32x4 zero = {0.f, 0.f, 0.f, 0.f};
    #pragma unroll
    for (int nt = 0; nt < 4; ++nt) acc[nt] = zero;

    #pragma unroll 4
    for (int ks = 0; ks < 16; ++ks) {
        const bf16x8 a = *(const bf16x8*)(ap + ks * 32);
        #pragma unroll
        for (int nt = 0; nt < 4; ++nt) {
            const bf16x8 bfr = *(const bf16x8*)(bp0 + (size_t)nt * 16 * NS + ks * 32);
            acc[nt] = __builtin_amdgcn_mfma_f32_16x16x32_bf16(a, bfr, acc[nt], 0, 0, 0);
        }
    }

    const int rr = (l >> 4) * 4;    // C/D: row = (lane>>4)*4 + reg, col = lane&15
    if (oT) {
        #pragma unroll
        for (int nt = 0; nt < 4; ++nt) {
            const int col = n0 + nt * 16 + lr;
            ushort4 pk;
            pk.x = f2bf(acc[nt][0]); pk.y = f2bf(acc[nt][1]);
            pk.z = f2bf(acc[nt][2]); pk.w = f2bf(acc[nt][3]);
            *(ushort4*)(oT + (size_t)col * NS + rowT + w * 16 + rr) = pk;
        }
    }
    if (oRM) {
        #pragma unroll
        for (int nt = 0; nt < 4; ++nt)
            #pragma unroll
            for (int r = 0; r < 4; ++r)
                lds[(w * 16 + rr + r) * 72 + nt * 16 + lr] = f2bf(acc[nt][r]);
        __syncthreads();
        const int r  = tid >> 2;             // 0..63
        const int c0 = (tid & 3) * 16;       // 0,16,32,48
        #pragma unroll
        for (int k = 0; k < 4; ++k) {
            const ushort4 q = *(const ushort4*)&lds[r * 72 + c0 + k * 4];
            *(ushort4*)(oRM + (size_t)r * NS + n0 + c0 + k * 4) = q;
        }
    }
}

// ---------------------------------------------------------------------------
// stage_kernel: one doubling stage. grid = E + (sq ? 64 : 0) blocks.
//  blocks [0,E):   expansion tiles: j = t>>3, n0 = (t&7)*64:
//                    out[j] (RM, 64x512 row-block) = Aop[j] (RM) x BTop-slice
//                  (L-levels: L[h+j] = L[j] * A^h; R-levels: R[dq+j]^T =
//                   R[j]^T * (A^{16dq})^T -- same index algebra both ways.)
//  blocks [E,E+64): squaring tiles: A^{2h} = A^h * A^h, RM (+T if sqOutT).
// ---------------------------------------------------------------------------
__global__ __launch_bounds__(256, 1) void stage_kernel(const u16* __restrict__ expAp,
                                                       const u16* __restrict__ expBT,
                                                       u16* __restrict__ expOut,
                                                       const u16* __restrict__ sqIn,
                                                       const u16* __restrict__ sqInT,
                                                       u16* __restrict__ sqOutRM,
                                                       u16* __restrict__ sqOutT,
                                                       int E)
{
    __shared__ u16 lds[64 * 72];   // 9,216 B bounce buffer
    const int t = blockIdx.x;
    if (t < E) {
        const int j = t >> 3, n0 = (t & 7) * 64;
        gemm_tile(expAp + (size_t)j * BLK, expBT, n0,
                  expOut + (size_t)j * BLK, nullptr, 0, lds);
    } else {
        const int tt = t - E;
        const int mr = tt >> 3, n0 = (tt & 7) * 64;
        gemm_tile(sqIn + (size_t)mr * BLK, sqInT, n0,
                  sqOutRM + (size_t)mr * BLK, sqOutT, mr * 64, lds);
    }
}

// ---------------------------------------------------------------------------
// g_kernel: G_m (m = blockIdx.x) via G^T = R_q^T x L_r  (q = m>>4, r = m&15):
//   Aop = R_q^T (RM [64][512]), BTop = L_r (RM [64][512]; BTop[c][k] =
//   L_r[c][k] = (L_r^T)[k][c] as required). acc[row=i][col=o] = G_m[o][i].
// Epilogue: bounce to lds[o][i], then the (round-3-validated) B-fragment
// swizzle read + D fold (m==0) + store to Gsw. grid = 128 blocks.
// ---------------------------------------------------------------------------
__global__ __launch_bounds__(256, 1) void g_kernel(const u16* __restrict__ Rt,
                                                   const u16* __restrict__ L,
                                                   const float* __restrict__ D,
                                                   u16* __restrict__ Gsw)
{
    __shared__ u16 lds[64 * 72];
    const int m = blockIdx.x;
    const int q = m >> 4, r = m & 15;
    const u16* ap0 = Rt + (size_t)q * BLK;
    const u16* bT0 = L  + (size_t)r * BLK;

    const int tid = threadIdx.x;
    const int w = tid >> 6, l = tid & 63;
    const int lr = l & 15, q8 = (l >> 4) * 8;

    const u16* ap  = ap0 + (size_t)(w * 16 + lr) * NS + q8;
    const u16* bp0 = bT0 + (size_t)lr * NS + q8;

    f32x4 acc[4];
    const f32x4 zero = {0.f, 0.f, 0.f, 0.f};
    #pragma unroll
    for (int nt = 0; nt < 4; ++nt) acc[nt] = zero;

    #pragma unroll 4
    for (int ks = 0; ks < 16; ++ks) {
        const bf16x8 a = *(const bf16x8*)(ap + ks * 32);
        #pragma unroll
        for (int nt = 0; nt < 4; ++nt) {
            const bf16x8 bfr = *(const bf16x8*)(bp0 + (size_t)nt * 16 * NS + ks * 32);
            acc[nt] = __builtin_amdgcn_mfma_f32_16x16x32_bf16(a, bfr, acc[nt], 0, 0, 0);
        }
    }

    // acc[nt][reg]: i (row) = w*16 + (l>>4)*4 + reg, o (col) = nt*16 + lr.
    const int rr = (l >> 4) * 4;
    #pragma unroll
    for (int nt = 0; nt < 4; ++nt)       // lds[o][i] = f2bf(G_m[o][i])
        #pragma unroll
        for (int rk = 0; rk < 4; ++rk)
            lds[(nt * 16 + lr) * 72 + (w * 16 + rr + rk)] = f2bf(acc[nt][rk]);
    __syncthreads();

    const int f = tid >> 6;              // 0..3
    #pragma unroll
    for (int f2 = 0; f2 < 8; f2 += 4) {  // fragments f and f+4
        const int fi = f2 + f;
        const int ks = fi >> 2, nt = fi & 3;
        const int o  = nt * 16 + (l & 15);
        const int i0 = ks * 32 + (l >> 4) * 8;
        u16 v[8];
        #pragma unroll
        for (int j = 0; j < 8; ++j) {
            u16 gv = lds[o * 72 + i0 + j];
            if (m == 0) gv = f2bf(bf2f(gv) + D[o * 64 + i0 + j]);
            v[j] = gv;
        }
        ushort4 p0; p0.x = v[0]; p0.y = v[1]; p0.z = v[2]; p0.w = v[3];
        ushort4 p1; p1.x = v[4]; p1.y = v[5]; p1.z = v[6]; p1.w = v[7];
        u16* dst = Gsw + ((size_t)(m * 8 + fi) * 64 + l) * 8;
        *(ushort4*)(dst + 0) = p0;
        *(ushort4*)(dst + 4) = p1;
    }
}

// ---------------------------------------------------------------------------
// conv_kernel: EXACT round-0 version (measured 78.5 us, MfmaUtil 37%).
// ---------------------------------------------------------------------------
__global__ __launch_bounds__(256, 2) void conv_kernel(const u16* __restrict__ xbf,
                                                      const u16* __restrict__ gsw,
                                                      float* __restrict__ y)
{
    __shared__ u16 Xs[XROWS * XSTR];   // 36,720 B -> >=2 blocks/CU

    const int tid = threadIdx.x;
    const int b  = blockIdx.y;
    const int t0 = blockIdx.x * CTILE;

    {
        const int g = tid & 7;
        int r = tid >> 3;
        const u16* src = xbf + ((size_t)b * PS + t0 + 1) * 64 + g * 8;
        #pragma unroll
        for (int it = 0; it < 8; ++it, r += 32) {
            if (r < XROWS) {
                const uint4 v = *(const uint4*)(src + (size_t)r * 64);
                *(uint4*)&Xs[r * XSTR + g * 8] = v;
            }
        }
    }
    __syncthreads();

    const int w    = tid >> 6;
    const int l    = tid & 63;
    const int lr   = l & 15;
    const int q8   = (l >> 4) * 8;
    const int wrow = w * 32;

    const uint4* gp = (const uint4*)gsw + l;
    uint4 bn[8];
    #pragma unroll
    for (int f = 0; f < 8; ++f) bn[f] = gp[f * 64];

    f32x4 acc[2][4];
    const f32x4 zero = {0.f, 0.f, 0.f, 0.f};
    #pragma unroll
    for (int mt = 0; mt < 2; ++mt)
        #pragma unroll
        for (int nt = 0; nt < 4; ++nt) acc[mt][nt] = zero;

    #pragma unroll 2
    for (int m = 0; m < TLAG; ++m) {
        bf16x8 bc[8];
        #pragma unroll
        for (int f = 0; f < 8; ++f) bc[f] = __builtin_bit_cast(bf16x8, bn[f]);
        if (m < TLAG - 1) {
            const uint4* gn = gp + (size_t)(m + 1) * 512;
            #pragma unroll
            for (int f = 0; f < 8; ++f) bn[f] = gn[f * 64];
        }

        const int rbase = wrow + lr + (TLAG - 1) - m;
        bf16x8 a[2][2];
        #pragma unroll
        for (int mt = 0; mt < 2; ++mt)
            #pragma unroll
            for (int ks = 0; ks < 2; ++ks)
                a[mt][ks] = *(const bf16x8*)&Xs[(rbase + mt * 16) * XSTR + ks * 32 + q8];

        #pragma unroll
        for (int ks = 0; ks < 2; ++ks)
            #pragma unroll
            for (int mt = 0; mt < 2; ++mt)
                #pragma unroll
                for (int nt = 0; nt < 4; ++nt)
                    acc[mt][nt] = __builtin_amdgcn_mfma_f32_16x16x32_bf16(
                        a[mt][ks], bc[ks * 4 + nt], acc[mt][nt], 0, 0, 0);
    }

    const int rr = (l >> 4) * 4;
    #pragma unroll
    for (int mt = 0; mt < 2; ++mt) {
        #pragma unroll
        for (int nt = 0; nt < 4; ++nt) {
            const int t = t0 + wrow + mt * 16 + rr;
            const int o = nt * 16 + lr;
            float* yp = y + ((size_t)b * SEQ + t) * 64 + o;
            #pragma unroll
            for (int r = 0; r < 4; ++r) yp[(size_t)r * 64] = acc[mt][nt][r];
        }
    }
}

// ---------------------------------------------------------------------------
// Workspace layout (bytes, 16-aligned):
//   0           xbf     8,650,752   (16 x 4224 x 64 bf16)
//   8,650,752   Arm       524,288   (A row-major)
//   9,175,040   At        524,288   (A^T)
//   9,699,328   A2rm      524,288
//  10,223,616   A2t       524,288
//  10,747,904   A4rm      524,288
//  11,272,192   A4t       524,288
//  11,796,480   A8rm      524,288
//  12,320,768   A8t       524,288
//  12,845,056   A16rm     524,288
//  13,369,344   A16t      524,288
//  13,893,632   A32rm     524,288
//  14,417,920   A32t      524,288
//  14,942,208   A64rm     524,288
//  15,466,496   BT         65,536   (B^T [64][512])
//  15,532,032   L       1,048,576   (L_r = C A^r, r<16, RM row-blocks)
//  16,580,608   Rt        524,288   (R_q^T = (A^{16q} B)^T, q<8)
//  17,104,896   Gsw     1,048,576   (B-fragment-swizzled conv kernels)
//  total: 18,153,472
// ---------------------------------------------------------------------------
extern "C" void kernel_launch(void* const* d_in, const int* in_sizes, int n_in,
                              void* d_out, int out_size, void* d_ws, size_t ws_size,
                              hipStream_t stream)
{
    const float* x = (const float*)d_in[0];
    const float* A = (const float*)d_in[1];
    const float* B = (const float*)d_in[2];
    const float* C = (const float*)d_in[3];
    const float* D = (const float*)d_in[4];
    float* y = (float*)d_out;

    char* w = (char*)d_ws;
    u16* xbf   = (u16*)(w + 0);
    u16* Arm   = (u16*)(w + 8650752);
    u16* At    = (u16*)(w + 9175040);
    u16* A2rm  = (u16*)(w + 9699328);
    u16* A2t   = (u16*)(w + 10223616);
    u16* A4rm  = (u16*)(w + 10747904);
    u16* A4t   = (u16*)(w + 11272192);
    u16* A8rm  = (u16*)(w + 11796480);
    u16* A8t   = (u16*)(w + 12320768);
    u16* A16rm = (u16*)(w + 12845056);
    u16* A16t  = (u16*)(w + 13369344);
    u16* A32rm = (u16*)(w + 13893632);
    u16* A32t  = (u16*)(w + 14417920);
    u16* A64rm = (u16*)(w + 14942208);
    u16* BT    = (u16*)(w + 15466496);
    u16* L     = (u16*)(w + 15532032);
    u16* Rt    = (u16*)(w + 16580608);
    u16* Gsw   = (u16*)(w + 17104896);

    prep_all<<<5504, 256, 0, stream>>>(x, A, B, C, xbf, Arm, At, BT, Rt, L);

    // Stage 1: L[1] = L[0]*A           ; A2  = A*A        (8 + 64 blocks)
    stage_kernel<<<72, 256, 0, stream>>>(L, At, L + 1 * BLK,
                                         Arm, At, A2rm, A2t, 8);
    // Stage 2: L[2+j] = L[j]*A2, j<2   ; A4  = A2*A2      (16 + 64)
    stage_kernel<<<80, 256, 0, stream>>>(L, A2t, L + 2 * BLK,
                                         A2rm, A2t, A4rm, A4t, 16);
    // Stage 3: L[4+j] = L[j]*A4, j<4   ; A8  = A4*A4      (32 + 64)
    stage_kernel<<<96, 256, 0, stream>>>(L, A4t, L + 4 * BLK,
                                         A4rm, A4t, A8rm, A8t, 32);
    // Stage 4: L[8+j] = L[j]*A8, j<8   ; A16 = A8*A8      (64 + 64)
    stage_kernel<<<128, 256, 0, stream>>>(L, A8t, L + 8 * BLK,
                                          A8rm, A8t, A16rm, A16t, 64);
    // Stage 5: R[1]^T = R[0]^T*A16^T   ; A32 = A16*A16    (8 + 64)
    stage_kernel<<<72, 256, 0, stream>>>(Rt, A16rm, Rt + 1 * BLK,
                                         A16rm, A16t, A32rm, A32t, 8);
    // Stage 6: R[2+j]^T = R[j]^T*A32^T ; A64 = A32*A32 (RM only) (16 + 64)
    stage_kernel<<<80, 256, 0, stream>>>(Rt, A32rm, Rt + 2 * BLK,
                                         A32rm, A32t, A64rm, nullptr, 16);
    // Stage 7: R[4+j]^T = R[j]^T*A64^T, j<4                (32)
    stage_kernel<<<32, 256, 0, stream>>>(Rt, A64rm, Rt + 4 * BLK,
                                         nullptr, nullptr, nullptr, nullptr, 32);
    // Stage 8: G_m = L_r R_q, swizzled + D fold            (128)
    g_kernel<<<128, 256, 0, stream>>>(Rt, L, D, Gsw);

    conv_kernel<<<dim3(SEQ / CTILE, BATCH), 256, 0, stream>>>(xbf, Gsw, y);
}